// Round 2
// baseline (238.549 us; speedup 1.0000x reference)
//
#include <hip/hip_runtime.h>
#include <stdint.h>

#define IMG_H 2048
#define IMG_W 2048
#define CH_PIX (IMG_H * IMG_W)      // 4194304
#define MAXDET 4096
#define NCH_HM 5
#define ROWS_PER_BLOCK 16
#define NBLK 640                    // 5 channels * (2048/16) row tiles
#define WPB 512                     // uint64 mask words per block (32768 px / 64)

__device__ __forceinline__ float sigmoidf_(float v) {
    return 1.0f / (1.0f + expf(-v));
}
__device__ __forceinline__ float sigthr_(float v) {
    float a = 1.0f / (1.0f + expf(-v));
    return a > 0.3f ? a : 0.0f;
}

// Load one row's 10-column window (8 own + 2 edge) of thresholded sigmoid.
__device__ __forceinline__ void load_row(const float* __restrict__ chan, int y,
                                         int xb, float* L) {
    if ((unsigned)y >= (unsigned)IMG_H) {
#pragma unroll
        for (int k = 0; k < 10; ++k) L[k] = 0.0f;
        return;
    }
    const float* row = chan + (size_t)y * IMG_W + xb;
    float4 a = *(const float4*)(row);
    float4 b = *(const float4*)(row + 4);
    L[1] = sigthr_(a.x); L[2] = sigthr_(a.y); L[3] = sigthr_(a.z); L[4] = sigthr_(a.w);
    L[5] = sigthr_(b.x); L[6] = sigthr_(b.y); L[7] = sigthr_(b.z); L[8] = sigthr_(b.w);
    L[0] = (xb > 0)            ? sigthr_(row[-1]) : 0.0f;
    L[9] = (xb + 8 < IMG_W)    ? sigthr_(row[8])  : 0.0f;
}

// Pass A: peak predicate -> byte-per-8-pixels mask (flat pixel order) + per-block counts.
// Block = one channel x 16 rows. Thread owns 8 contiguous columns. Barrier-free main loop.
__global__ __launch_bounds__(256) void pass_a(const float* __restrict__ feat,
                                              uint8_t* __restrict__ mask_bytes,
                                              unsigned* __restrict__ counts) {
    int blk = blockIdx.x;
    int c = blk >> 7;               // / 128
    int ytile = blk & 127;
    int y0 = ytile << 4;            // * 16
    const float* chan = feat + (size_t)c * CH_PIX;
    int t = threadIdx.x;
    int xb = t << 3;                // 8t

    float tp[10], tc[10], tn[10];
    load_row(chan, y0 - 1, xb, tp);
    load_row(chan, y0,     xb, tc);

    unsigned wcnt = 0;
    size_t byte_base = (size_t)c * (CH_PIX / 8) + (size_t)y0 * (IMG_W / 8) + t;

    for (int r = 0; r < ROWS_PER_BLOCK; ++r) {
        load_row(chan, y0 + r + 1, xb, tn);
        float cm[10];
#pragma unroll
        for (int k = 0; k < 10; ++k) cm[k] = fmaxf(fmaxf(tp[k], tc[k]), tn[k]);
        unsigned byte = 0;
#pragma unroll
        for (int j = 0; j < 8; ++j) {
            float own = tc[j + 1];
            float pooled = fmaxf(fmaxf(cm[j], cm[j + 1]), cm[j + 2]);
            if (own > 0.0f && pooled == own) byte |= (1u << j);
        }
        mask_bytes[byte_base + (size_t)r * (IMG_W / 8)] = (uint8_t)byte;
        wcnt += __popc(byte);
#pragma unroll
        for (int k = 0; k < 10; ++k) { tp[k] = tc[k]; tc[k] = tn[k]; }
    }

#pragma unroll
    for (int off = 32; off; off >>= 1) wcnt += __shfl_down(wcnt, off, 64);
    __shared__ unsigned s[4];
    int wave = t >> 6, lane = t & 63;
    if (lane == 0) s[wave] = wcnt;
    __syncthreads();
    if (t == 0) counts[blk] = s[0] + s[1] + s[2] + s[3];
}

__device__ __forceinline__ void emit_word(uint64_t w, uint64_t pbase, unsigned& rank,
                                          const float* __restrict__ feat,
                                          float* __restrict__ out) {
    while (w) {
        int b = __ffsll((unsigned long long)w) - 1;
        w &= w - 1;
        if (rank < MAXDET) {
            uint64_t p = pbase + (uint64_t)b;
            int c = (int)(p >> 22);                 // / CH_PIX
            int rem = (int)(p & (CH_PIX - 1));
            int y = rem >> 11, x = rem & 2047;
            size_t pix = (size_t)y * IMG_W + x;
            float pm = sigmoidf_(feat[pix]);
#pragma unroll
            for (int ch = 1; ch < NCH_HM; ++ch)
                pm = fmaxf(pm, sigmoidf_(feat[(size_t)ch * CH_PIX + pix]));
            float sdv = sigmoidf_(feat[(size_t)5 * CH_PIX + pix]);
            float szv = sigmoidf_(feat[(size_t)6 * CH_PIX + pix]);
            out[rank] = pm;
            out[MAXDET + rank * 3 + 0] = (float)c;
            out[MAXDET + rank * 3 + 1] = (float)y;
            out[MAXDET + rank * 3 + 2] = (float)x;
            out[4 * MAXDET + rank] = szv;           // size_width
            out[5 * MAXDET + rank] = szv;           // size_height
            out[6 * MAXDET + rank] = sdv;           // side_sel
        }
        rank++;
    }
}

// Pass C: per-block offset from counts reduce, ordered emit of first MAXDET, tail zero.
__global__ __launch_bounds__(256) void pass_c(const float* __restrict__ feat,
                                              const uint64_t* __restrict__ masks,
                                              const unsigned* __restrict__ counts,
                                              float* __restrict__ out) {
    int blk = blockIdx.x;
    int t = threadIdx.x;

    unsigned p_lt = 0, p_all = 0;
    for (int i = t; i < NBLK; i += 256) {
        unsigned v = counts[i];
        p_all += v;
        if (i < blk) p_lt += v;
    }
#pragma unroll
    for (int off = 32; off; off >>= 1) {
        p_lt  += __shfl_down(p_lt,  off, 64);
        p_all += __shfl_down(p_all, off, 64);
    }
    __shared__ unsigned sl[4], sa[4];
    int wave = t >> 6, lane = t & 63;
    if (lane == 0) { sl[wave] = p_lt; sa[wave] = p_all; }
    __syncthreads();
    unsigned boff  = sl[0] + sl[1] + sl[2] + sl[3];
    unsigned total = sa[0] + sa[1] + sa[2] + sa[3];

    if (blk == NBLK - 1) {
        unsigned start = total < MAXDET ? total : MAXDET;
        for (unsigned k = start + t; k < MAXDET; k += 256) {
            out[k] = 0.0f;
            out[MAXDET + 3 * k + 0] = 0.0f;
            out[MAXDET + 3 * k + 1] = 0.0f;
            out[MAXDET + 3 * k + 2] = 0.0f;
            out[4 * MAXDET + k] = 0.0f;
            out[5 * MAXDET + k] = 0.0f;
            out[6 * MAXDET + k] = 0.0f;
        }
    }
    if (boff >= MAXDET) return;   // uniform: nearly all blocks exit here

    uint64_t w0 = masks[(size_t)blk * WPB + 2 * t];
    uint64_t w1 = masks[(size_t)blk * WPB + 2 * t + 1];
    unsigned cnt = (unsigned)__popcll(w0) + (unsigned)__popcll(w1);
    __shared__ unsigned tmp[256];
    tmp[t] = cnt;
    __syncthreads();
    for (int off = 1; off < 256; off <<= 1) {
        unsigned u = (t >= off) ? tmp[t - off] : 0u;
        __syncthreads();
        tmp[t] += u;
        __syncthreads();
    }
    unsigned rank = boff + tmp[t] - cnt;
    uint64_t pbase = (uint64_t)blk * 32768ull + (uint64_t)t * 128ull;
    emit_word(w0, pbase,      rank, feat, out);
    emit_word(w1, pbase + 64, rank, feat, out);
}

extern "C" void kernel_launch(void* const* d_in, const int* in_sizes, int n_in,
                              void* d_out, int out_size, void* d_ws, size_t ws_size,
                              hipStream_t stream) {
    const float* feat = (const float*)d_in[0];
    float* out = (float*)d_out;
    uint8_t* mask_bytes = (uint8_t*)d_ws;                       // 2.62 MB
    unsigned* counts = (unsigned*)((char*)d_ws + (size_t)NBLK * WPB * 8);

    pass_a<<<NBLK, 256, 0, stream>>>(feat, mask_bytes, counts);
    pass_c<<<NBLK, 256, 0, stream>>>(feat, (const uint64_t*)mask_bytes, counts, out);
}

// Round 3
// 183.161 us; speedup vs baseline: 1.3024x; 1.3024x over previous
//
#include <hip/hip_runtime.h>
#include <stdint.h>
#include <math.h>

#define IMG_H 2048
#define IMG_W 2048
#define CH_PIX (IMG_H * IMG_W)     // 4194304
#define MAXDET 4096
#define R_PB 8                     // rows per pass_a block
#define NBLK 1280                  // 5 channels * 256 row-tiles

__device__ __forceinline__ float sigmoidf_(float v) {
    return 1.0f / (1.0f + expf(-v));
}
__device__ __forceinline__ float sigthr_(float v) {
    float a = 1.0f / (1.0f + expf(-v));
    return a > 0.3f ? a : 0.0f;
}
__device__ __forceinline__ float max3_(float a, float b, float c) {
    return fmaxf(fmaxf(a, b), c);
}

// Pass A: peak predicate -> byte-per-8-pixels mask (flat pixel order) + per-block counts.
// Block = one channel x 8 full rows (256 threads x 8 cols = 2048 cols).
// Column neighbors exchanged via shfl; lanes 0/63 load one edge column scalar.
__global__ __launch_bounds__(256) void pass_a(const float* __restrict__ feat,
                                              uint8_t* __restrict__ mask_bytes,
                                              unsigned* __restrict__ counts) {
    int blk = blockIdx.x;
    int c = blk >> 8;               // 256 row-tiles per channel
    int ytile = blk & 255;
    int y0 = ytile << 3;
    const float* chan = feat + (size_t)c * CH_PIX;
    int t = threadIdx.x;
    int lane = t & 63;
    int xb = t << 3;                // own cols xb..xb+7
    // edge column owned by boundary lanes: lane0 -> xb-1, lane63 -> xb+8
    int xe = (lane == 0) ? (xb - 1) : (xb + 8);
    bool edge_lane = (lane == 0) || (lane == 63);
    bool edge_ok = edge_lane && ((unsigned)xe < (unsigned)IMG_W);

    float sp[8], sc[8], sn[8];
    float ep, ec, en;

    auto load8 = [&](int y, float* s, float& e) {
        if ((unsigned)y >= (unsigned)IMG_H) {
#pragma unroll
            for (int j = 0; j < 8; ++j) s[j] = 0.0f;
            e = 0.0f;
            return;
        }
        const float* row = chan + (size_t)y * IMG_W;
        float4 a = *(const float4*)(row + xb);
        float4 b = *(const float4*)(row + xb + 4);
        float rv = -INFINITY;                 // sigthr(-inf) = 0
        if (edge_ok) rv = row[xe];
        s[0] = sigthr_(a.x); s[1] = sigthr_(a.y); s[2] = sigthr_(a.z); s[3] = sigthr_(a.w);
        s[4] = sigthr_(b.x); s[5] = sigthr_(b.y); s[6] = sigthr_(b.z); s[7] = sigthr_(b.w);
        e = sigthr_(rv);
    };

    load8(y0 - 1, sp, ep);
    load8(y0,     sc, ec);

    unsigned cnt = 0;
    size_t bb = (size_t)c * (CH_PIX / 8) + (size_t)y0 * (IMG_W / 8) + t;

    for (int r = 0; r < R_PB; ++r) {
        load8(y0 + r + 1, sn, en);
        float cm[8];
#pragma unroll
        for (int j = 0; j < 8; ++j) cm[j] = max3_(sp[j], sc[j], sn[j]);
        float cme = max3_(ep, ec, en);
        float cmL = __shfl_up(cm[7], 1, 64);
        float cmR = __shfl_down(cm[0], 1, 64);
        if (lane == 0)  cmL = cme;
        if (lane == 63) cmR = cme;
        unsigned byte = 0;
#pragma unroll
        for (int j = 0; j < 8; ++j) {
            float l  = j       ? cm[j - 1] : cmL;
            float rr = (j < 7) ? cm[j + 1] : cmR;
            float pooled = max3_(l, cm[j], rr);
            if (sc[j] > 0.0f && pooled == sc[j]) byte |= (1u << j);
        }
        mask_bytes[bb + (size_t)r * (IMG_W / 8)] = (uint8_t)byte;
        cnt += __popc(byte);
#pragma unroll
        for (int j = 0; j < 8; ++j) { sp[j] = sc[j]; sc[j] = sn[j]; }
        ep = ec; ec = en;
    }

#pragma unroll
    for (int off = 32; off; off >>= 1) cnt += __shfl_down(cnt, off, 64);
    __shared__ unsigned s4[4];
    if (lane == 0) s4[t >> 6] = cnt;
    __syncthreads();
    if (t == 0) counts[blk] = s4[0] + s4[1] + s4[2] + s4[3];
}

// Pass B: per-block offset via counts reduce; bit-loop emits pixel ids to LDS
// (stores only, no latency chain); then parallel per-detection gather. Tail zero.
__global__ __launch_bounds__(256) void pass_b(const float* __restrict__ feat,
                                              const uint64_t* __restrict__ masks,
                                              const unsigned* __restrict__ counts,
                                              float* __restrict__ out) {
    int blk = blockIdx.x;
    int t = threadIdx.x;
    int wave = t >> 6, lane = t & 63;

    unsigned p_lt = 0, p_all = 0;
    for (int i = t; i < NBLK; i += 256) {
        unsigned v = counts[i];
        p_all += v;
        if (i < blk) p_lt += v;
    }
#pragma unroll
    for (int off = 32; off; off >>= 1) {
        p_lt  += __shfl_down(p_lt,  off, 64);
        p_all += __shfl_down(p_all, off, 64);
    }
    __shared__ unsigned sl[4], sa[4];
    if (lane == 0) { sl[wave] = p_lt; sa[wave] = p_all; }
    __syncthreads();
    unsigned boff  = sl[0] + sl[1] + sl[2] + sl[3];
    unsigned total = sa[0] + sa[1] + sa[2] + sa[3];

    if (blk == NBLK - 1) {           // zero the invalid tail
        unsigned start = total < MAXDET ? total : MAXDET;
        for (unsigned k = start + t; k < MAXDET; k += 256) {
            out[k] = 0.0f;
            out[MAXDET + 3 * k + 0] = 0.0f;
            out[MAXDET + 3 * k + 1] = 0.0f;
            out[MAXDET + 3 * k + 2] = 0.0f;
            out[4 * MAXDET + k] = 0.0f;
            out[5 * MAXDET + k] = 0.0f;
            out[6 * MAXDET + k] = 0.0f;
        }
    }
    if (boff >= MAXDET) return;      // uniform early exit for nearly all blocks

    uint64_t w = masks[(size_t)blk * 256 + t];   // this block's 16384 pixels
    unsigned cnt = (unsigned)__popcll(w);
    __shared__ unsigned tmp[256];
    __shared__ uint32_t det_lds[MAXDET];
    tmp[t] = cnt;
    __syncthreads();
    for (int off = 1; off < 256; off <<= 1) {
        unsigned u = (t >= off) ? tmp[t - off] : 0u;
        __syncthreads();
        tmp[t] += u;
        __syncthreads();
    }
    unsigned rank = boff + tmp[t] - cnt;
    unsigned bsum = tmp[255];
    uint32_t pbase = (uint32_t)blk * 16384u + (uint32_t)t * 64u;
    while (w) {                       // stores only -- fast even serial
        int b = __ffsll((unsigned long long)w) - 1;
        w &= w - 1;
        if (rank < MAXDET) det_lds[rank - boff] = pbase + (uint32_t)b;
        rank++;
    }
    __syncthreads();

    unsigned nend = boff + bsum; if (nend > MAXDET) nend = MAXDET;
    unsigned nloc = nend - boff;
    for (unsigned k = t; k < nloc; k += 256) {    // parallel independent gathers
        uint32_t p = det_lds[k];
        unsigned rk = boff + k;
        int c = (int)(p >> 22);
        int rem = (int)(p & (CH_PIX - 1));
        int y = rem >> 11, x = rem & 2047;
        size_t pix = (size_t)y * IMG_W + x;
        float pm = sigmoidf_(feat[pix]);
#pragma unroll
        for (int ch = 1; ch < 5; ++ch)
            pm = fmaxf(pm, sigmoidf_(feat[(size_t)ch * CH_PIX + pix]));
        float sdv = sigmoidf_(feat[(size_t)5 * CH_PIX + pix]);
        float szv = sigmoidf_(feat[(size_t)6 * CH_PIX + pix]);
        out[rk] = pm;
        out[MAXDET + 3 * rk + 0] = (float)c;
        out[MAXDET + 3 * rk + 1] = (float)y;
        out[MAXDET + 3 * rk + 2] = (float)x;
        out[4 * MAXDET + rk] = szv;   // size_width
        out[5 * MAXDET + rk] = szv;   // size_height
        out[6 * MAXDET + rk] = sdv;   // side_sel
    }
}

extern "C" void kernel_launch(void* const* d_in, const int* in_sizes, int n_in,
                              void* d_out, int out_size, void* d_ws, size_t ws_size,
                              hipStream_t stream) {
    const float* feat = (const float*)d_in[0];
    float* out = (float*)d_out;
    uint8_t* mask_bytes = (uint8_t*)d_ws;                        // 2.62 MB
    unsigned* counts = (unsigned*)((char*)d_ws + (size_t)NBLK * 2048);

    pass_a<<<NBLK, 256, 0, stream>>>(feat, mask_bytes, counts);
    pass_b<<<NBLK, 256, 0, stream>>>(feat, (const uint64_t*)d_ws, counts, out);
}